// Round 24
// baseline (74.001 us; speedup 1.0000x reference)
//
#include <hip/hip_runtime.h>
#include <climits>

#define KNN 32
#define NPTS 16384
#define MCTR 4096
#define BATCH 4
#define CFEAT 64
#define NBINS 1000     // 10x10x10, pitch 0.1
#define HITCAP 128
#define CPW 4
#define WCHUNKS 8
#define FPAD 34        // k-major LDS pitch for 32-ch half (float2-aligned)

typedef float f4 __attribute__((ext_vector_type(4)));

// PREDICATE — DO NOT TOUCH (bit-exact vs grader ref, resolved rounds 0-8):
//   c2/p2: seed-y tree:  fma(z,z, fma(x,x, rn(y*y)))
//   cp:    seed-x chain: fma(z,pz, fma(y,py, rn(x*px)))
//   d2 = rn(rn(c2+p2) - rn(2*cp));  valid = d2 < (float)(0.1*0.1)
__device__ __forceinline__ bool ball_pred(float cx, float cy, float cz, float c2,
                                          float px, float py, float pz) {
    const float r2 = 0.009999999776482582f;
    const float p2 = __fmaf_rn(pz, pz, __fmaf_rn(px, px, __fmul_rn(py, py)));
    const float cp = __fmaf_rn(cz, pz, __fmaf_rn(cy, py, __fmul_rn(cx, px)));
    const float d2 = __fsub_rn(__fadd_rn(c2, p2), __fmul_rn(2.0f, cp));
    return d2 < r2;
}

__device__ __forceinline__ int bin_of(float x, float y, float z) {
    int bx = min(max((int)(x * 10.0f), 0), 9);
    int by = min(max((int)(y * 10.0f), 0), 9);
    int bz = min(max((int)(z * 10.0f), 0), 9);
    return (bx * 10 + by) * 10 + bz;
}

// ---------------------------------------------------------------------------
// prep_all (R20/R22, unchanged): transpose (256 blocks) + bin_prep (4 blocks),
// one dispatch. Intermediates CACHEABLE (R21 lesson: NT bypasses L3 too).
// ---------------------------------------------------------------------------
__global__ __launch_bounds__(1024) void prep_all(
    const float* __restrict__ feats, float* __restrict__ featsT,
    const float* __restrict__ points, int* __restrict__ binStart,
    f4* __restrict__ sP, f4* __restrict__ pointsT)
{
    __shared__ float tl[64][65];    // transpose tile
    __shared__ int hist[NBINS];     // bin_prep
    __shared__ int scanbuf[1024];

    const int t = threadIdx.x;
    if (blockIdx.x < BATCH * 64) {
        // ---- transpose: 4 sequential 64ch x 64n tiles ----
        const int blk = blockIdx.x;
        const int b = blk >> 6;
        const int n_base = (blk & 63) * 256;
        const float* f = feats  + (size_t)b * CFEAT * NPTS;
        float* ft      = featsT + (size_t)b * NPTS * CFEAT;
        const int nl = t & 63, cq = t >> 6;     // cq 0..15 (uniform per wave)
        const int quad = t & 15, n_s = t >> 4;  // store: 4x256B rows per wave
        for (int tile = 0; tile < 4; ++tile) {
            const int n0 = n_base + tile * 64;
#pragma unroll
            for (int r = 0; r < 4; ++r) {
                const int ch = r * 16 + cq;
                tl[ch][nl] = __builtin_nontemporal_load(&f[(size_t)ch * NPTS + n0 + nl]);
            }
            __syncthreads();
            f4 o;
            o.x = tl[4 * quad + 0][n_s];
            o.y = tl[4 * quad + 1][n_s];
            o.z = tl[4 * quad + 2][n_s];
            o.w = tl[4 * quad + 3][n_s];
            *reinterpret_cast<f4*>(&ft[(size_t)(n0 + n_s) * CFEAT + 4 * quad]) = o;
            __syncthreads();
        }
        return;
    }

    // ---- bin_prep for batch b ----
    const int b = blockIdx.x - BATCH * 64;
    const float* pc = points + (size_t)b * 3 * NPTS;
    const size_t gb = (size_t)b * NPTS;

    if (t < NBINS) hist[t] = 0;
    __syncthreads();

    f4 myp[16];
    int mybin[16];
#pragma unroll
    for (int r = 0; r < 16; ++r) {
        const int i = r * 1024 + t;
        const float x = pc[i], y = pc[NPTS + i], z = pc[2 * NPTS + i];
        myp[r] = (f4){x, y, z, __int_as_float(i)};
        pointsT[gb + i] = (f4){x, y, z, 0.0f};
        const int bn = bin_of(x, y, z);
        mybin[r] = bn;
        atomicAdd(&hist[bn], 1);
    }
    __syncthreads();

    const int v = (t < NBINS) ? hist[t] : 0;
    scanbuf[t] = v;
    __syncthreads();
    for (int off = 1; off < 1024; off <<= 1) {
        const int u = (t >= off) ? scanbuf[t - off] : 0;
        __syncthreads();
        scanbuf[t] += u;
        __syncthreads();
    }
    const int excl = scanbuf[t] - v;
    if (t < NBINS) binStart[b * (NBINS + 1) + t] = excl;
    if (t == 0)    binStart[b * (NBINS + 1) + NBINS] = NPTS;
    __syncthreads();
    if (t < NBINS) hist[t] = excl;     // cursors
    __syncthreads();

#pragma unroll
    for (int r = 0; r < 16; ++r) {
        const int pos = atomicAdd(&hist[mybin[r]], 1);
        sP[gb + pos] = myp[r];
    }
}

// ---------------------------------------------------------------------------
// Kernel A (round-24 split): scan + sort -> idx ONLY. One wave per center,
// LDS = 512B hits -> max occupancy, short kernel. Writes idx[32] coalesced
// CACHEABLE (re-read by the SAME XCD in kernel B via identical swizzle).
// Rationale: R23 model says the fused wave's long serial chain (scan+sort+
// gather) left stores bursting at ~40% duty -> 2.5TB/s effective. Splitting
// gives kernel B a pure load->store steady state.
// ---------------------------------------------------------------------------
__global__ __launch_bounds__(64) void bq_sort_kernel(
    const float* __restrict__ points, const float* __restrict__ centers,
    const int* __restrict__ binStart, const f4* __restrict__ sP,
    int* __restrict__ idx_out)
{
    __shared__ int hits[HITCAP];
    const int lane = threadIdx.x;
    const int cls = blockIdx.x & 7;
    const int b   = cls >> 1;                                  // 0..3
    const int m   = ((cls & 1) << 11) | (blockIdx.x >> 3);     // 0..4095
    const int gw  = b * MCTR + m;

    const float* cc = centers + (size_t)b * 3 * MCTR;
    const float cx = cc[m], cy = cc[MCTR + m], cz = cc[2 * MCTR + m];
    const float c2 = __fmaf_rn(cz, cz, __fmaf_rn(cx, cx, __fmul_rn(cy, cy)));

    hits[lane] = INT_MAX;
    hits[lane + 64] = INT_MAX;

    const float rg = 0.1001f;
    const int xlo = max((int)((cx - rg) * 10.0f), 0), xhi = min((int)((cx + rg) * 10.0f), 9);
    const int ylo = max((int)((cy - rg) * 10.0f), 0), yhi = min((int)((cy + rg) * 10.0f), 9);
    const int zlo = max((int)((cz - rg) * 10.0f), 0), zhi = min((int)((cz + rg) * 10.0f), 9);

    const int base = b * NPTS;
    const int* bs = binStart + b * (NBINS + 1);

    // flattened segment bounds (R22) + register-distributed sweep (R23)
    int segS[9], pre[9];
    int T = 0;
#pragma unroll
    for (int gx = 0; gx < 3; ++gx) {
#pragma unroll
        for (int gy = 0; gy < 3; ++gy) {
            const int g = gx * 3 + gy;
            const int X = min(xlo + gx, 9);
            const int Y = min(ylo + gy, 9);
            const bool ok = (xlo + gx <= xhi) && (ylo + gy <= yhi);
            const int cb = (X * 10 + Y) * 10;
            const int sv = bs[cb + zlo];
            const int ev = bs[cb + zhi + 1];
            segS[g] = sv;
            pre[g] = T;
            T += ok ? (ev - sv) : 0;
        }
    }

    int cnt = 0;
    for (int slot0 = 0; slot0 < T; slot0 += 64) {
        const int slot = slot0 + lane;
        int addr = 0;
#pragma unroll
        for (int g = 0; g < 9; ++g) {
            if (slot >= pre[g]) addr = segS[g] + (slot - pre[g]);
        }
        const bool in = slot < T;
        const f4 P = in ? sP[base + addr] : (f4){1e9f, 1e9f, 1e9f, 0.0f};
        const bool valid = in && ball_pred(cx, cy, cz, c2, P.x, P.y, P.z);
        const unsigned long long mask = __ballot(valid);
        if (mask) {
            const int prefix = __popcll(mask & ((1ull << lane) - 1ull));
            const int ppos = cnt + prefix;
            if (valid && ppos < HITCAP) hits[ppos] = __float_as_int(P.w);
            cnt += __popcll(mask);
        }
    }

    int fidx;
    if (cnt > HITCAP) {
        // exact fallback: linear scan in index order (statistically never)
        const float* pc = points + (size_t)b * 3 * NPTS;
        int cnt2 = 0, firstIdx = 0;
        for (int j0 = 0; j0 < NPTS; j0 += 64) {
            const int j = j0 + lane;
            const bool valid = ball_pred(cx, cy, cz, c2, pc[j], pc[NPTS + j], pc[2 * NPTS + j]);
            const unsigned long long mask = __ballot(valid);
            if (mask) {
                if (cnt2 == 0) firstIdx = j0 + __builtin_ctzll(mask);
                const int prefix = __popcll(mask & ((1ull << lane) - 1ull));
                if (valid && (cnt2 + prefix) < KNN) hits[cnt2 + prefix] = j;
                cnt2 += __popcll(mask);
                if (cnt2 >= KNN) break;
            }
        }
        const int first = (cnt2 == 0) ? 0 : firstIdx;
        fidx = (lane < cnt2 && lane < KNN) ? hits[lane] : first;
    } else {
        int a  = hits[lane];
        int v2 = hits[lane + 64];
#pragma unroll
        for (int k = 2; k <= 128; k <<= 1) {
#pragma unroll
            for (int j = 64; j >= 1; j >>= 1) {
                if (j > (k >> 1)) continue;
                if (j == 64) {
                    const int lo = min(a, v2), hi = max(a, v2);
                    a = lo; v2 = hi;
                } else {
                    const bool lower = (lane & j) == 0;
                    const bool upA = (lane & k) == 0;
                    const bool upB = ((lane + 64) & k) == 0;
                    const int va = __shfl_xor(a, j);
                    a = (lower == upA) ? min(a, va) : max(a, va);
                    const int vb = __shfl_xor(v2, j);
                    v2 = (lower == upB) ? min(v2, vb) : max(v2, vb);
                }
            }
        }
        const int first = __shfl(a, 0);
        fidx = (lane < cnt) ? a : ((cnt == 0) ? 0 : first);
    }

    if (lane < KNN) idx_out[(size_t)gw * KNN + lane] = fidx;
}

// ---------------------------------------------------------------------------
// Kernel B (round-24 split): PURE STREAMING GATHER. One wave per center,
// no scan/sort -> serial chain ~3x shorter; waves live in load->store
// steady state so the NT write stream saturates. Same XCD swizzle as A.
// ---------------------------------------------------------------------------
__global__ __launch_bounds__(64) void gather_kernel(
    const float* __restrict__ centers, const int* __restrict__ idx,
    const f4* __restrict__ pointsT, const float* __restrict__ featsT,
    float* __restrict__ out)
{
    __shared__ float lfeat[KNN][FPAD];
    const int lane = threadIdx.x;
    const int cls = blockIdx.x & 7;
    const int b   = cls >> 1;                                  // 0..3
    const int m   = ((cls & 1) << 11) | (blockIdx.x >> 3);     // 0..4095
    const int gw  = b * MCTR + m;
    const int base = b * NPTS;

    const float* cc = centers + (size_t)b * 3 * MCTR;
    const float cx = cc[m], cy = cc[MCTR + m], cz = cc[2 * MCTR + m];

    const int fidx = idx[(size_t)gw * KNN + (lane & 31)];

    float* obase = out + ((size_t)b * 67 * MCTR + m) * KNN;

    if (lane < 32) {
        const f4 P = pointsT[(size_t)base + fidx];
        __builtin_nontemporal_store(P.x - cx, &obase[lane]);
        __builtin_nontemporal_store(P.y - cy, &obase[(size_t)MCTR * KNN + lane]);
        __builtin_nontemporal_store(P.z - cz, &obase[(size_t)2 * MCTR * KNN + lane]);
    }

    const float* ft = featsT + (size_t)b * NPTS * CFEAT;
    const int pp = lane >> 3;     // 0..7 point-within-sweep
    const int q  = lane & 7;      // 0..7 channel quad (within half)
    const int ch8 = lane >> 3;    // 0..7 channel-within-iter
    const int kq  = lane & 7;     // 0..7 float4 chunk along k
#pragma unroll
    for (int h = 0; h < 2; ++h) {
#pragma unroll
        for (int s = 0; s < 4; ++s) {
            const int k = s * 8 + pp;
            const int ik = __shfl(fidx, k);
            const float4 v = *reinterpret_cast<const float4*>(
                ft + (size_t)ik * CFEAT + h * 32 + q * 4);
            *reinterpret_cast<float2*>(&lfeat[k][4 * q])     = make_float2(v.x, v.y);
            *reinterpret_cast<float2*>(&lfeat[k][4 * q + 2]) = make_float2(v.z, v.w);
        }
#pragma unroll
        for (int it = 0; it < 4; ++it) {
            const int cw = it * 8 + ch8;
            const int ch = h * 32 + cw;
            f4 o;
            o.x = lfeat[4 * kq + 0][cw];
            o.y = lfeat[4 * kq + 1][cw];
            o.z = lfeat[4 * kq + 2][cw];
            o.w = lfeat[4 * kq + 3][cw];
            __builtin_nontemporal_store(o,
                reinterpret_cast<f4*>(&obase[(size_t)(3 + ch) * MCTR * KNN + 4 * kq]));
        }
    }
}

// ---------------------------------------------------------------------------
// Fallback path (ws too small): full-scan bq + direct gather.
// ---------------------------------------------------------------------------
__global__ __launch_bounds__(256) void ball_query_kernel(
    const float* __restrict__ points, const float* __restrict__ centers,
    int* __restrict__ idx_out)
{
    const int wave = (blockIdx.x * blockDim.x + threadIdx.x) >> 6;
    const int lane = threadIdx.x & 63;
    const int wavesPerBatch = MCTR / CPW;
    const int b = wave / wavesPerBatch;
    const int m0 = (wave % wavesPerBatch) * CPW;

    const float* pc = points + (size_t)b * 3 * NPTS;
    const float* cc = centers + (size_t)b * 3 * MCTR;

    float cx[CPW], cy[CPW], cz[CPW], c2[CPW];
    int cnt[CPW], firstIdx[CPW];
#pragma unroll
    for (int c = 0; c < CPW; ++c) {
        cx[c] = cc[m0 + c]; cy[c] = cc[MCTR + m0 + c]; cz[c] = cc[2 * MCTR + m0 + c];
        c2[c] = __fmaf_rn(cz[c], cz[c], __fmaf_rn(cx[c], cx[c], __fmul_rn(cy[c], cy[c])));
        cnt[c] = 0; firstIdx[c] = 0;
    }
    int* outbase = idx_out + ((size_t)b * MCTR + m0) * KNN;

    for (int w = 0; w < NPTS / (64 * WCHUNKS); ++w) {
        const int base = w * 64 * WCHUNKS + lane;
        float px[WCHUNKS], py[WCHUNKS], pz[WCHUNKS];
#pragma unroll
        for (int u = 0; u < WCHUNKS; ++u) {
            px[u] = pc[base + 64 * u];
            py[u] = pc[NPTS + base + 64 * u];
            pz[u] = pc[2 * NPTS + base + 64 * u];
        }
#pragma unroll
        for (int u = 0; u < WCHUNKS; ++u) {
            const int j0 = w * 64 * WCHUNKS + 64 * u;
            const int j = j0 + lane;
#pragma unroll
            for (int c = 0; c < CPW; ++c) {
                const bool valid = ball_pred(cx[c], cy[c], cz[c], c2[c], px[u], py[u], pz[u]);
                const unsigned long long mask = __ballot(valid);
                if (mask) {
                    if (cnt[c] == 0) firstIdx[c] = j0 + __builtin_ctzll(mask);
                    const int prefix = __popcll(mask & ((1ull << lane) - 1ull));
                    if (valid && (cnt[c] + prefix) < KNN)
                        outbase[c * KNN + cnt[c] + prefix] = j;
                    cnt[c] += __popcll(mask);
                }
            }
        }
        bool alldone = true;
#pragma unroll
        for (int c = 0; c < CPW; ++c) alldone &= (cnt[c] >= KNN);
        if (alldone) break;
    }
#pragma unroll
    for (int c = 0; c < CPW; ++c) {
        if (cnt[c] < KNN && lane >= cnt[c] && lane < KNN)
            outbase[c * KNN + lane] = firstIdx[c];
    }
}

__global__ __launch_bounds__(256) void gather_direct_kernel(
    const float* __restrict__ points, const float* __restrict__ centers,
    const float* __restrict__ feats, const int* __restrict__ idx,
    float* __restrict__ out)
{
    const long long t = (long long)blockIdx.x * blockDim.x + threadIdx.x;
    const int k = (int)(t & (KNN - 1));
    long long r = t >> 5;
    const int m = (int)(r & (MCTR - 1));
    r >>= 12;
    const int ch = (int)(r % 67);
    const int b = (int)(r / 67);
    const int i = idx[((size_t)(b * MCTR + m)) * KNN + k];
    float v;
    if (ch < 3) {
        v = points[(size_t)b * 3 * NPTS + (size_t)ch * NPTS + i]
          - centers[(size_t)b * 3 * MCTR + (size_t)ch * MCTR + m];
    } else {
        v = feats[(size_t)b * CFEAT * NPTS + (size_t)(ch - 3) * NPTS + i];
    }
    out[t] = v;
}

extern "C" void kernel_launch(void* const* d_in, const int* in_sizes, int n_in,
                              void* d_out, int out_size, void* d_ws, size_t ws_size,
                              hipStream_t stream) {
    const float* points  = nullptr;
    const float* centers = nullptr;
    const float* feats   = nullptr;
    for (int i = 0; i < n_in; ++i) {
        if (in_sizes[i] == BATCH * 3 * NPTS)      points  = (const float*)d_in[i];
        else if (in_sizes[i] == BATCH * 3 * MCTR) centers = (const float*)d_in[i];
        else if (in_sizes[i] == BATCH * CFEAT * NPTS) feats = (const float*)d_in[i];
    }
    float* out = (float*)d_out;

    size_t off = 0;
    auto carve = [&](size_t bytes) -> void* {
        void* p = (char*)d_ws + off;
        off = (off + bytes + 255) & ~(size_t)255;
        return p;
    };
    int*   idx      = (int*)  carve((size_t)BATCH * MCTR * KNN * 4);
    float* featsT   = (float*)carve((size_t)BATCH * NPTS * CFEAT * 4);
    int*   binStart = (int*)  carve((size_t)BATCH * (NBINS + 1) * 4);
    f4*    sP       = (f4*)   carve((size_t)BATCH * NPTS * 16);
    f4*    pointsT  = (f4*)   carve((size_t)BATCH * NPTS * 16);
    const size_t neededFull = off;

    if (ws_size >= neededFull) {
        prep_all<<<BATCH * 64 + BATCH, 1024, 0, stream>>>(
            feats, featsT, points, binStart, sP, pointsT);
        bq_sort_kernel<<<BATCH * MCTR, 64, 0, stream>>>(
            points, centers, binStart, sP, idx);
        gather_kernel<<<BATCH * MCTR, 64, 0, stream>>>(
            centers, idx, pointsT, featsT, out);
    } else {
        const int nThreads1 = (BATCH * MCTR / CPW) * 64;
        ball_query_kernel<<<nThreads1 / 256, 256, 0, stream>>>(points, centers, idx);
        const long long total = (long long)BATCH * 67 * MCTR * KNN;
        gather_direct_kernel<<<(int)(total / 256), 256, 0, stream>>>(points, centers, feats, idx, out);
    }
}

// Round 25
// 61.300 us; speedup vs baseline: 1.2072x; 1.2072x over previous
//
#include <hip/hip_runtime.h>
#include <climits>

#define KNN 32
#define NPTS 16384
#define MCTR 4096
#define BATCH 4
#define CFEAT 64
#define NBINS 1000     // 10x10x10, pitch 0.1
#define HITCAP 128
#define CPW 4
#define WCHUNKS 8
#define FPAD 34        // k-major LDS pitch for 32-ch half (float2-aligned)

typedef float f4 __attribute__((ext_vector_type(4)));

// PREDICATE — DO NOT TOUCH (bit-exact vs grader ref, resolved rounds 0-8):
//   c2/p2: seed-y tree:  fma(z,z, fma(x,x, rn(y*y)))
//   cp:    seed-x chain: fma(z,pz, fma(y,py, rn(x*px)))
//   d2 = rn(rn(c2+p2) - rn(2*cp));  valid = d2 < (float)(0.1*0.1)
__device__ __forceinline__ bool ball_pred(float cx, float cy, float cz, float c2,
                                          float px, float py, float pz) {
    const float r2 = 0.009999999776482582f;
    const float p2 = __fmaf_rn(pz, pz, __fmaf_rn(px, px, __fmul_rn(py, py)));
    const float cp = __fmaf_rn(cz, pz, __fmaf_rn(cy, py, __fmul_rn(cx, px)));
    const float d2 = __fsub_rn(__fadd_rn(c2, p2), __fmul_rn(2.0f, cp));
    return d2 < r2;
}

__device__ __forceinline__ int bin_of(float x, float y, float z) {
    int bx = min(max((int)(x * 10.0f), 0), 9);
    int by = min(max((int)(y * 10.0f), 0), 9);
    int bz = min(max((int)(z * 10.0f), 0), 9);
    return (bx * 10 + by) * 10 + bz;
}

// ---------------------------------------------------------------------------
// prep_all (R20/R22): transpose (256 blocks) + bin_prep (4 blocks), one
// dispatch. Intermediates CACHEABLE (R21 lesson: NT bypasses L3 too).
// ---------------------------------------------------------------------------
__global__ __launch_bounds__(1024) void prep_all(
    const float* __restrict__ feats, float* __restrict__ featsT,
    const float* __restrict__ points, int* __restrict__ binStart,
    f4* __restrict__ sP, f4* __restrict__ pointsT)
{
    __shared__ float tl[64][65];    // transpose tile
    __shared__ int hist[NBINS];     // bin_prep
    __shared__ int scanbuf[1024];

    const int t = threadIdx.x;
    if (blockIdx.x < BATCH * 64) {
        // ---- transpose: 4 sequential 64ch x 64n tiles ----
        const int blk = blockIdx.x;
        const int b = blk >> 6;
        const int n_base = (blk & 63) * 256;
        const float* f = feats  + (size_t)b * CFEAT * NPTS;
        float* ft      = featsT + (size_t)b * NPTS * CFEAT;
        const int nl = t & 63, cq = t >> 6;     // cq 0..15 (uniform per wave)
        const int quad = t & 15, n_s = t >> 4;  // store: 4x256B rows per wave
        for (int tile = 0; tile < 4; ++tile) {
            const int n0 = n_base + tile * 64;
#pragma unroll
            for (int r = 0; r < 4; ++r) {
                const int ch = r * 16 + cq;
                tl[ch][nl] = __builtin_nontemporal_load(&f[(size_t)ch * NPTS + n0 + nl]);
            }
            __syncthreads();
            f4 o;
            o.x = tl[4 * quad + 0][n_s];
            o.y = tl[4 * quad + 1][n_s];
            o.z = tl[4 * quad + 2][n_s];
            o.w = tl[4 * quad + 3][n_s];
            *reinterpret_cast<f4*>(&ft[(size_t)(n0 + n_s) * CFEAT + 4 * quad]) = o;
            __syncthreads();
        }
        return;
    }

    // ---- bin_prep for batch b ----
    const int b = blockIdx.x - BATCH * 64;
    const float* pc = points + (size_t)b * 3 * NPTS;
    const size_t gb = (size_t)b * NPTS;

    if (t < NBINS) hist[t] = 0;
    __syncthreads();

    f4 myp[16];
    int mybin[16];
#pragma unroll
    for (int r = 0; r < 16; ++r) {
        const int i = r * 1024 + t;
        const float x = pc[i], y = pc[NPTS + i], z = pc[2 * NPTS + i];
        myp[r] = (f4){x, y, z, __int_as_float(i)};
        pointsT[gb + i] = (f4){x, y, z, 0.0f};
        const int bn = bin_of(x, y, z);
        mybin[r] = bn;
        atomicAdd(&hist[bn], 1);
    }
    __syncthreads();

    const int v = (t < NBINS) ? hist[t] : 0;
    scanbuf[t] = v;
    __syncthreads();
    for (int off = 1; off < 1024; off <<= 1) {
        const int u = (t >= off) ? scanbuf[t - off] : 0;
        __syncthreads();
        scanbuf[t] += u;
        __syncthreads();
    }
    const int excl = scanbuf[t] - v;
    if (t < NBINS) binStart[b * (NBINS + 1) + t] = excl;
    if (t == 0)    binStart[b * (NBINS + 1) + NBINS] = NPTS;
    __syncthreads();
    if (t < NBINS) hist[t] = excl;     // cursors
    __syncthreads();

#pragma unroll
    for (int r = 0; r < 16; ++r) {
        const int pos = atomicAdd(&hist[mybin[r]], 1);
        sP[gb + pos] = myp[r];
    }
}

// ---------------------------------------------------------------------------
// FUSED kernel (R23, best verified: 61.5us): scan+sort+gather in one wave.
// R24 lesson: do NOT split — fused waves at different progress points mix
// scan-loads and NT-stores continuously (free phase overlap); splitting
// serialized the phases globally and cost +12.5us.
// ---------------------------------------------------------------------------
__global__ __launch_bounds__(64) void bq_gather_fused(
    const float* __restrict__ points, const float* __restrict__ centers,
    const int* __restrict__ binStart, const f4* __restrict__ sP,
    const f4* __restrict__ pointsT, const float* __restrict__ featsT,
    float* __restrict__ out)
{
    __shared__ int hits[HITCAP];
    __shared__ float lfeat[KNN][FPAD];
    const int lane = threadIdx.x;
    const int cls = blockIdx.x & 7;
    const int b   = cls >> 1;                                  // 0..3
    const int m   = ((cls & 1) << 11) | (blockIdx.x >> 3);     // 0..4095

    const float* cc = centers + (size_t)b * 3 * MCTR;
    const float cx = cc[m], cy = cc[MCTR + m], cz = cc[2 * MCTR + m];
    const float c2 = __fmaf_rn(cz, cz, __fmaf_rn(cx, cx, __fmul_rn(cy, cy)));

    hits[lane] = INT_MAX;
    hits[lane + 64] = INT_MAX;

    const float rg = 0.1001f;
    const int xlo = max((int)((cx - rg) * 10.0f), 0), xhi = min((int)((cx + rg) * 10.0f), 9);
    const int ylo = max((int)((cy - rg) * 10.0f), 0), yhi = min((int)((cy + rg) * 10.0f), 9);
    const int zlo = max((int)((cz - rg) * 10.0f), 0), zhi = min((int)((cz + rg) * 10.0f), 9);

    const int base = b * NPTS;
    const int* bs = binStart + b * (NBINS + 1);

    // flattened segment bounds: 18 unconditional loads, full MLP
    int segS[9], pre[9];
    int T = 0;
#pragma unroll
    for (int gx = 0; gx < 3; ++gx) {
#pragma unroll
        for (int gy = 0; gy < 3; ++gy) {
            const int g = gx * 3 + gy;
            const int X = min(xlo + gx, 9);
            const int Y = min(ylo + gy, 9);
            const bool ok = (xlo + gx <= xhi) && (ylo + gy <= yhi);
            const int cb = (X * 10 + Y) * 10;
            const int sv = bs[cb + zlo];
            const int ev = bs[cb + zhi + 1];
            segS[g] = sv;
            pre[g] = T;
            T += ok ? (ev - sv) : 0;
        }
    }

    // register-distributed sweep over concatenated candidates
    int cnt = 0;
    for (int slot0 = 0; slot0 < T; slot0 += 64) {
        const int slot = slot0 + lane;
        int addr = 0;
#pragma unroll
        for (int g = 0; g < 9; ++g) {
            if (slot >= pre[g]) addr = segS[g] + (slot - pre[g]);
        }
        const bool in = slot < T;
        const f4 P = in ? sP[base + addr] : (f4){1e9f, 1e9f, 1e9f, 0.0f};
        const bool valid = in && ball_pred(cx, cy, cz, c2, P.x, P.y, P.z);
        const unsigned long long mask = __ballot(valid);
        if (mask) {
            const int prefix = __popcll(mask & ((1ull << lane) - 1ull));
            const int ppos = cnt + prefix;
            if (valid && ppos < HITCAP) hits[ppos] = __float_as_int(P.w);
            cnt += __popcll(mask);
        }
    }

    int fidx;
    if (cnt > HITCAP) {
        // exact fallback: linear scan in index order (statistically never)
        const float* pc = points + (size_t)b * 3 * NPTS;
        int cnt2 = 0, firstIdx = 0;
        for (int j0 = 0; j0 < NPTS; j0 += 64) {
            const int j = j0 + lane;
            const bool valid = ball_pred(cx, cy, cz, c2, pc[j], pc[NPTS + j], pc[2 * NPTS + j]);
            const unsigned long long mask = __ballot(valid);
            if (mask) {
                if (cnt2 == 0) firstIdx = j0 + __builtin_ctzll(mask);
                const int prefix = __popcll(mask & ((1ull << lane) - 1ull));
                if (valid && (cnt2 + prefix) < KNN) hits[cnt2 + prefix] = j;
                cnt2 += __popcll(mask);
                if (cnt2 >= KNN) break;
            }
        }
        const int first = (cnt2 == 0) ? 0 : firstIdx;
        fidx = (lane < cnt2 && lane < KNN) ? hits[lane] : first;
    } else {
        int a  = hits[lane];
        int v2 = hits[lane + 64];
#pragma unroll
        for (int k = 2; k <= 128; k <<= 1) {
#pragma unroll
            for (int j = 64; j >= 1; j >>= 1) {
                if (j > (k >> 1)) continue;
                if (j == 64) {
                    const int lo = min(a, v2), hi = max(a, v2);
                    a = lo; v2 = hi;
                } else {
                    const bool lower = (lane & j) == 0;
                    const bool upA = (lane & k) == 0;
                    const bool upB = ((lane + 64) & k) == 0;
                    const int va = __shfl_xor(a, j);
                    a = (lower == upA) ? min(a, va) : max(a, va);
                    const int vb = __shfl_xor(v2, j);
                    v2 = (lower == upB) ? min(v2, vb) : max(v2, vb);
                }
            }
        }
        const int first = __shfl(a, 0);
        fidx = (lane < cnt) ? a : ((cnt == 0) ? 0 : first);
    }

    float* obase = out + ((size_t)b * 67 * MCTR + m) * KNN;

    if (lane < 32) {
        const f4 P = pointsT[(size_t)base + fidx];
        __builtin_nontemporal_store(P.x - cx, &obase[lane]);
        __builtin_nontemporal_store(P.y - cy, &obase[(size_t)MCTR * KNN + lane]);
        __builtin_nontemporal_store(P.z - cz, &obase[(size_t)2 * MCTR * KNN + lane]);
    }

    const float* ft = featsT + (size_t)b * NPTS * CFEAT;
    const int pp = lane >> 3;     // 0..7 point-within-sweep
    const int q  = lane & 7;      // 0..7 channel quad (within half)
    const int ch8 = lane >> 3;    // 0..7 channel-within-iter
    const int kq  = lane & 7;     // 0..7 float4 chunk along k
#pragma unroll
    for (int h = 0; h < 2; ++h) {
#pragma unroll
        for (int s = 0; s < 4; ++s) {
            const int k = s * 8 + pp;
            const int ik = __shfl(fidx, k);
            const float4 v = *reinterpret_cast<const float4*>(
                ft + (size_t)ik * CFEAT + h * 32 + q * 4);
            *reinterpret_cast<float2*>(&lfeat[k][4 * q])     = make_float2(v.x, v.y);
            *reinterpret_cast<float2*>(&lfeat[k][4 * q + 2]) = make_float2(v.z, v.w);
        }
#pragma unroll
        for (int it = 0; it < 4; ++it) {
            const int cw = it * 8 + ch8;
            const int ch = h * 32 + cw;
            f4 o;
            o.x = lfeat[4 * kq + 0][cw];
            o.y = lfeat[4 * kq + 1][cw];
            o.z = lfeat[4 * kq + 2][cw];
            o.w = lfeat[4 * kq + 3][cw];
            __builtin_nontemporal_store(o,
                reinterpret_cast<f4*>(&obase[(size_t)(3 + ch) * MCTR * KNN + 4 * kq]));
        }
    }
}

// ---------------------------------------------------------------------------
// Fallback path (ws too small): full-scan bq + direct gather.
// ---------------------------------------------------------------------------
__global__ __launch_bounds__(256) void ball_query_kernel(
    const float* __restrict__ points, const float* __restrict__ centers,
    int* __restrict__ idx_out)
{
    const int wave = (blockIdx.x * blockDim.x + threadIdx.x) >> 6;
    const int lane = threadIdx.x & 63;
    const int wavesPerBatch = MCTR / CPW;
    const int b = wave / wavesPerBatch;
    const int m0 = (wave % wavesPerBatch) * CPW;

    const float* pc = points + (size_t)b * 3 * NPTS;
    const float* cc = centers + (size_t)b * 3 * MCTR;

    float cx[CPW], cy[CPW], cz[CPW], c2[CPW];
    int cnt[CPW], firstIdx[CPW];
#pragma unroll
    for (int c = 0; c < CPW; ++c) {
        cx[c] = cc[m0 + c]; cy[c] = cc[MCTR + m0 + c]; cz[c] = cc[2 * MCTR + m0 + c];
        c2[c] = __fmaf_rn(cz[c], cz[c], __fmaf_rn(cx[c], cx[c], __fmul_rn(cy[c], cy[c])));
        cnt[c] = 0; firstIdx[c] = 0;
    }
    int* outbase = idx_out + ((size_t)b * MCTR + m0) * KNN;

    for (int w = 0; w < NPTS / (64 * WCHUNKS); ++w) {
        const int base = w * 64 * WCHUNKS + lane;
        float px[WCHUNKS], py[WCHUNKS], pz[WCHUNKS];
#pragma unroll
        for (int u = 0; u < WCHUNKS; ++u) {
            px[u] = pc[base + 64 * u];
            py[u] = pc[NPTS + base + 64 * u];
            pz[u] = pc[2 * NPTS + base + 64 * u];
        }
#pragma unroll
        for (int u = 0; u < WCHUNKS; ++u) {
            const int j0 = w * 64 * WCHUNKS + 64 * u;
            const int j = j0 + lane;
#pragma unroll
            for (int c = 0; c < CPW; ++c) {
                const bool valid = ball_pred(cx[c], cy[c], cz[c], c2[c], px[u], py[u], pz[u]);
                const unsigned long long mask = __ballot(valid);
                if (mask) {
                    if (cnt[c] == 0) firstIdx[c] = j0 + __builtin_ctzll(mask);
                    const int prefix = __popcll(mask & ((1ull << lane) - 1ull));
                    if (valid && (cnt[c] + prefix) < KNN)
                        outbase[c * KNN + cnt[c] + prefix] = j;
                    cnt[c] += __popcll(mask);
                }
            }
        }
        bool alldone = true;
#pragma unroll
        for (int c = 0; c < CPW; ++c) alldone &= (cnt[c] >= KNN);
        if (alldone) break;
    }
#pragma unroll
    for (int c = 0; c < CPW; ++c) {
        if (cnt[c] < KNN && lane >= cnt[c] && lane < KNN)
            outbase[c * KNN + lane] = firstIdx[c];
    }
}

__global__ __launch_bounds__(256) void gather_direct_kernel(
    const float* __restrict__ points, const float* __restrict__ centers,
    const float* __restrict__ feats, const int* __restrict__ idx,
    float* __restrict__ out)
{
    const long long t = (long long)blockIdx.x * blockDim.x + threadIdx.x;
    const int k = (int)(t & (KNN - 1));
    long long r = t >> 5;
    const int m = (int)(r & (MCTR - 1));
    r >>= 12;
    const int ch = (int)(r % 67);
    const int b = (int)(r / 67);
    const int i = idx[((size_t)(b * MCTR + m)) * KNN + k];
    float v;
    if (ch < 3) {
        v = points[(size_t)b * 3 * NPTS + (size_t)ch * NPTS + i]
          - centers[(size_t)b * 3 * MCTR + (size_t)ch * MCTR + m];
    } else {
        v = feats[(size_t)b * CFEAT * NPTS + (size_t)(ch - 3) * NPTS + i];
    }
    out[t] = v;
}

extern "C" void kernel_launch(void* const* d_in, const int* in_sizes, int n_in,
                              void* d_out, int out_size, void* d_ws, size_t ws_size,
                              hipStream_t stream) {
    const float* points  = nullptr;
    const float* centers = nullptr;
    const float* feats   = nullptr;
    for (int i = 0; i < n_in; ++i) {
        if (in_sizes[i] == BATCH * 3 * NPTS)      points  = (const float*)d_in[i];
        else if (in_sizes[i] == BATCH * 3 * MCTR) centers = (const float*)d_in[i];
        else if (in_sizes[i] == BATCH * CFEAT * NPTS) feats = (const float*)d_in[i];
    }
    float* out = (float*)d_out;

    size_t off = 0;
    auto carve = [&](size_t bytes) -> void* {
        void* p = (char*)d_ws + off;
        off = (off + bytes + 255) & ~(size_t)255;
        return p;
    };
    int*   idx      = (int*)  carve((size_t)BATCH * MCTR * KNN * 4);
    float* featsT   = (float*)carve((size_t)BATCH * NPTS * CFEAT * 4);
    int*   binStart = (int*)  carve((size_t)BATCH * (NBINS + 1) * 4);
    f4*    sP       = (f4*)   carve((size_t)BATCH * NPTS * 16);
    f4*    pointsT  = (f4*)   carve((size_t)BATCH * NPTS * 16);
    const size_t neededFull = off;

    if (ws_size >= neededFull) {
        prep_all<<<BATCH * 64 + BATCH, 1024, 0, stream>>>(
            feats, featsT, points, binStart, sP, pointsT);
        bq_gather_fused<<<BATCH * MCTR, 64, 0, stream>>>(
            points, centers, binStart, sP, pointsT, featsT, out);
    } else {
        const int nThreads1 = (BATCH * MCTR / CPW) * 64;
        ball_query_kernel<<<nThreads1 / 256, 256, 0, stream>>>(points, centers, idx);
        const long long total = (long long)BATCH * 67 * MCTR * KNN;
        gather_direct_kernel<<<(int)(total / 256), 256, 0, stream>>>(points, centers, feats, idx, out);
    }
}